// Round 3
// baseline (211.371 us; speedup 1.0000x reference)
//
#include <hip/hip_runtime.h>
#include <hip/hip_bf16.h>
#include <stdint.h>

// Problem dims
#define B_DIM 16
#define L_DIM 512
#define DM    1024
#define DF    4096

typedef __attribute__((ext_vector_type(8))) __bf16 bf16x8;
typedef __attribute__((ext_vector_type(4))) float  f32x4;

#define GLOBAL_AS __attribute__((address_space(1)))
#define LDS_AS    __attribute__((address_space(3)))

__device__ __forceinline__ unsigned short f2bf(float f){
    unsigned u = __float_as_uint(f);
    u += 0x7fffu + ((u >> 16) & 1u);      // RNE
    return (unsigned short)(u >> 16);
}

__device__ __forceinline__ void gll16(const void* g, void* l){
    __builtin_amdgcn_global_load_lds((const GLOBAL_AS uint32_t*)g,
                                     (LDS_AS uint32_t*)l, 16, 0, 0);
}

// ---------- W0 [1024][4096] f32 -> W0T [4096][1024] bf16 (transpose + cast) ----------
__global__ void k_w0t(const float* __restrict__ W0, unsigned short* __restrict__ W0T){
    __shared__ float tile[32][33];
    int k0 = blockIdx.x * 32;                 // 32 K-tiles
    int n0 = blockIdx.y * 32;                 // 128 N-tiles
    int tc = threadIdx.x & 31, tr = threadIdx.x >> 5;
    #pragma unroll
    for (int p = 0; p < 4; ++p){
        int k = tr + p*8;
        tile[k][tc] = W0[(size_t)(k0 + k)*DF + n0 + tc];
    }
    __syncthreads();
    #pragma unroll
    for (int p = 0; p < 4; ++p){
        int n = tr + p*8;
        W0T[(size_t)(n0 + n)*DM + k0 + tc] = f2bf(tile[tc][n]);
    }
}

// ---------- cumsum over L, 3 phases (chunk=64) ----------
// phase1: P[b][c][d] = sum_{j in chunk c} x[b][j][d]
__global__ void k_psum(const float* __restrict__ x, float* __restrict__ P){
    int blk = blockIdx.x;                     // 512 blocks
    int dch = blk & 3, c = (blk >> 2) & 7, b = blk >> 5;
    int d = dch*256 + threadIdx.x;
    const float* p = x + ((size_t)(b*L_DIM) + c*64)*DM + d;
    float acc = 0.f;
    #pragma unroll 8
    for (int j = 0; j < 64; ++j) acc += p[(size_t)j*DM];
    P[((size_t)(b*8) + c)*DM + d] = acc;
}

// phase2: exclusive scan over c (in place)
__global__ void k_scanP(float* __restrict__ P){
    int blk = blockIdx.x;                     // 64 blocks
    int b = blk >> 2, dch = blk & 3;
    int d = dch*256 + threadIdx.x;
    float run = 0.f;
    #pragma unroll
    for (int c = 0; c < 8; ++c){
        size_t idx = ((size_t)(b*8) + c)*DM + d;
        float v = P[idx];
        P[idx] = run;
        run += v;
    }
}

// phase3: s = prefix + local cumsum, cast bf16
__global__ void k_csum(const float* __restrict__ x, const float* __restrict__ P,
                       unsigned short* __restrict__ S){
    int blk = blockIdx.x;                     // 512 blocks
    int dch = blk & 3, c = (blk >> 2) & 7, b = blk >> 5;
    int d = dch*256 + threadIdx.x;
    size_t rowbase = (size_t)(b*L_DIM) + c*64;
    const float* p = x + rowbase*DM + d;
    unsigned short* q = S + rowbase*DM + d;
    float acc = P[((size_t)(b*8) + c)*DM + d];
    #pragma unroll 8
    for (int j = 0; j < 64; ++j){
        acc += p[(size_t)j*DM];
        q[(size_t)j*DM] = f2bf(acc);
    }
}

// ---------- GEMM: g[row] += sum_n relu( S[row,:] . W0T[n,:] ) ----------
// 128x128 tile, BK=32, 4 waves (2x2), 16x16x32 bf16 MFMA, m97-style 2-barrier loop.
__global__ void __launch_bounds__(256)
k_gemm(const unsigned short* __restrict__ S, const unsigned short* __restrict__ W0T,
       float* __restrict__ g){
    __shared__ __bf16 As[128*32];   // [m][k], 64B rows
    __shared__ __bf16 Bs[128*32];   // [n][k]
    const int tid  = threadIdx.x;
    const int w    = tid >> 6, lane = tid & 63;
    const int wr   = w >> 1,  wc   = w & 1;
    const int lr   = lane & 15, lh = lane >> 4;
    const int row0 = blockIdx.y * 128;        // 64 m-tiles
    const int n0   = blockIdx.x * 128;        // 32 n-tiles

    f32x4 acc[4][4] = {};
    for (int kt = 0; kt < DM; kt += 32){
        __syncthreads();                      // prev tile fully consumed
        #pragma unroll
        for (int s = 0; s < 2; ++s){
            int ch = s*256 + tid;             // 16B chunk id; 4 chunks per 32-elem row
            gll16(S   + ((size_t)(row0 + (ch >> 2))*DM + kt + (ch & 3)*8),
                  (void*)(As + (s*256 + w*64)*8));
            gll16(W0T + ((size_t)(n0   + (ch >> 2))*DM + kt + (ch & 3)*8),
                  (void*)(Bs + (s*256 + w*64)*8));
        }
        __syncthreads();                      // compiler drains vmcnt before barrier
        bf16x8 af[4], bf[4];
        #pragma unroll
        for (int mi = 0; mi < 4; ++mi)
            af[mi] = *(const bf16x8*)(As + (wr*64 + mi*16 + lr)*32 + lh*8);
        #pragma unroll
        for (int ni = 0; ni < 4; ++ni)
            bf[ni] = *(const bf16x8*)(Bs + (wc*64 + ni*16 + lr)*32 + lh*8);
        #pragma unroll
        for (int mi = 0; mi < 4; ++mi)
            #pragma unroll
            for (int ni = 0; ni < 4; ++ni)
                acc[mi][ni] = __builtin_amdgcn_mfma_f32_16x16x32_bf16(
                                  af[mi], bf[ni], acc[mi][ni], 0, 0, 0);
    }

    // relu + column-sum (wave covers 64 cols) + 16-lane reduce + atomic row add
    #pragma unroll
    for (int mi = 0; mi < 4; ++mi){
        float v[4] = {0.f, 0.f, 0.f, 0.f};
        #pragma unroll
        for (int ni = 0; ni < 4; ++ni)
            #pragma unroll
            for (int r = 0; r < 4; ++r)
                v[r] += fmaxf(acc[mi][ni][r], 0.f);
        #pragma unroll
        for (int off = 1; off < 16; off <<= 1)
            #pragma unroll
            for (int r = 0; r < 4; ++r)
                v[r] += __shfl_xor(v[r], off, 64);
        if (lr == 0){
            int row = row0 + wr*64 + mi*16 + lh*4;  // C/D: row=(lane>>4)*4+reg
            #pragma unroll
            for (int r = 0; r < 4; ++r)
                atomicAdd(&g[row + r], v[r]);
        }
    }
}

// ---------- t = per-b inclusive scan of g ----------
__global__ void k_scan_t(const float* __restrict__ g, float* __restrict__ t){
    __shared__ float lds[512];
    int b = blockIdx.x, i = threadIdx.x;
    lds[i] = g[b*512 + i];
    __syncthreads();
    for (int off = 1; off < 512; off <<= 1){
        float add = (i >= off) ? lds[i - off] : 0.f;
        __syncthreads();
        lds[i] += add;
        __syncthreads();
    }
    t[b*512 + i] = lds[i];
}

// ---------- W1 [1024][512] -> W1T [512][1024] ----------
__global__ void k_w1t(const float* __restrict__ W1, float* __restrict__ W1T){
    __shared__ float tile[32][33];
    int i0 = blockIdx.x * 32;                 // 16 i-tiles
    int d0 = blockIdx.y * 32;                 // 32 d-tiles
    int tc = threadIdx.x & 31, tr = threadIdx.x >> 5;
    #pragma unroll
    for (int p = 0; p < 4; ++p){
        int dl = tr + p*8;
        tile[dl][tc] = W1[(size_t)(d0 + dl)*L_DIM + i0 + tc];
    }
    __syncthreads();
    #pragma unroll
    for (int p = 0; p < 4; ++p){
        int il = tr + p*8;
        W1T[(size_t)(i0 + il)*DM + d0 + tc] = tile[tc][il];
    }
}

// ---------- out[b,i,d] = t[b,i] * W1T[i,d] ----------
__global__ void k_out(const float* __restrict__ t, const float* __restrict__ W1T,
                      float* __restrict__ out){
    int b = blockIdx.x >> 9, i = blockIdx.x & 511;
    float tv = t[b*512 + i];
    const float4* wp = (const float4*)(W1T + (size_t)i*DM);
    float4* op = (float4*)(out + ((size_t)(b*512 + i))*DM);
    float4 wv = wp[threadIdx.x];
    op[threadIdx.x] = make_float4(tv*wv.x, tv*wv.y, tv*wv.z, tv*wv.w);
}

extern "C" void kernel_launch(void* const* d_in, const int* in_sizes, int n_in,
                              void* d_out, int out_size, void* d_ws, size_t ws_size,
                              hipStream_t stream){
    const float* x  = (const float*)d_in[0];
    const float* W0 = (const float*)d_in[1];
    const float* W1 = (const float*)d_in[2];
    float* out = (float*)d_out;

    char* ws = (char*)d_ws;
    unsigned short* W0T = (unsigned short*)ws;                        // 8 MB
    unsigned short* S   = (unsigned short*)(ws + (8u<<20));           // 16 MB
    float* P   = (float*)(ws + (24u<<20));                            // 512 KB
    float* gv  = (float*)(ws + (24u<<20) + (512u<<10));               // 32 KB
    float* tv  = (float*)(ws + (24u<<20) + (544u<<10));               // 32 KB
    float* W1T = (float*)(ws + (25u<<20));                            // 2 MB

    hipMemsetAsync(gv, 0, 8192*sizeof(float), stream);
    k_w0t  <<<dim3(32,128), 256, 0, stream>>>(W0, W0T);
    k_psum <<<512, 256, 0, stream>>>(x, P);
    k_scanP<<<64, 256, 0, stream>>>(P);
    k_csum <<<512, 256, 0, stream>>>(x, P, S);
    k_gemm <<<dim3(32,64), 256, 0, stream>>>(S, W0T, gv);
    k_scan_t<<<16, 512, 0, stream>>>(gv, tv);
    k_w1t  <<<dim3(16,32), 256, 0, stream>>>(W1, W1T);
    k_out  <<<8192, 256, 0, stream>>>(tv, W1T, out);
}